// Round 6
// baseline (714.519 us; speedup 1.0000x reference)
//
#include <hip/hip_runtime.h>
#include <hip/hip_fp16.h>
#include <stdint.h>

// SNNClassifier: B=16384, F=256, H=256, C=10, T=100
// Phase 1: layer-1 LIF spike bitmask into d_ws (100 x 16384 x 256 bits).
// Phase 2: persistent-state fused kernel, int8 fused-digit GEMM:
//   W*2^14 = a*64 + b (a,b int8 digits); h = (sum a*(64 z) + b*z)*2^-14
//   via mfma_i32_16x16x64_i8 with A-operands {64z, z} - single exact i32
//   accumulator, one fp32 rounding at the end.
//
// R6 changes (R5: snn_main 306us, MfmaUtil 29%, Occupancy 20.7% = ~1.65
// waves/SIMD -> MFMA pipe of one wave can't overlap VALU of another; the
// i8 MFMA floor is ~109us and VALU floor ~100us, so overlap is the gap):
//  1. ONE block per CU: block = 1024 thr (16 waves), h-tile = 256 (all of
//     W in LDS: 2 digits x 256 x 256 = 128KB, laid out as 4 x 32KB per-hc
//     slabs so every wave's ds_reads use one base + <32KB imm offsets).
//     grid = 256 = exactly 1 block/CU -> 4 waves/SIMD co-resident, hard.
//     Per-wave loop shape identical to R5's proven no-spill structure.
//     Bonus: Z read exactly once (52MB, was 4x).
//  2. __umul24 for the nibble spread (v_mul_lo_u32 is quarter-rate; u24 is
//     full-rate), 64x per tg per lane.
//  3. b-digit clamp +-127 (8-sigma safety; a-digit already clamped).

#define BB 16384
#define FF 256
#define HH 256
#define CC 10
#define TT 100

typedef __attribute__((ext_vector_type(4))) int int4v;

// ---------------- kernel 1: layer-1 spike bitmask ----------------
// Block = 256 thr = 4 waves; wave owns 4 b-values x 4 segs (16 LIF states
// per thread). Per t, lanes 0..15 store 16 u64 = 128B contiguous.
__global__ __launch_bounds__(256) void spike_gen(
    const float* __restrict__ x, unsigned long long* __restrict__ Z) {
  const int lane = threadIdx.x & 63;
  const int wv   = threadIdx.x >> 6;
  const int b0   = blockIdx.x * 16 + wv * 4;  // this wave's 4 b-values
  const float K_VM = (float)(0.001 * 100.0);        // 0.1f, numpy-exact
  const float K_ID = (float)(1.0 - 0.001 * 200.0);  // 0.8f, numpy-exact

  float v[16], cur[16], xv[16];
#pragma unroll
  for (int jb = 0; jb < 4; ++jb)
#pragma unroll
    for (int js = 0; js < 4; ++js) {
      const int idx = jb * 4 + js;
      xv[idx] = x[(size_t)(b0 + jb) * FF + js * 64 + lane];
      v[idx] = 0.0f; cur[idx] = 0.0f;
    }

  unsigned long long mymask = 0;
  unsigned long long* zp = Z + (size_t)b0 * 4;  // row slot base (u64 units)

  for (int t = 0; t < TT; ++t) {
#pragma unroll
    for (int idx = 0; idx < 16; ++idx) {
      float vd   = __fadd_rn(v[idx], __fmul_rn(K_VM, __fadd_rn(-v[idx], cur[idx])));
      float idec = __fmul_rn(cur[idx], K_ID);
      bool z = (vd > 1.0f);
      unsigned long long m = __ballot(z);
      if (lane == idx) mymask = m;  // lane idx owns slot (b0+jb)*4+js
      v[idx]   = z ? 0.0f : vd;
      cur[idx] = __fadd_rn(idec, xv[idx]);
    }
    if (lane < 16) zp[(size_t)t * (BB * 4) + lane] = mymask;
  }
}

// ---------------- kernel 2: fused temporal loop (i8) ----------------
// grid: 256 blocks (1/CU), block = 1024 thr = 16 waves.
// wave (wv = tid>>6): hc = wv>>2 (h-chunk of 64), bsub = wv&3 (b-subtile
// of 16). Block covers b-tile 64 x all 256 h.
// LDS: 4 slabs of 32KB (one per hc). Slab = 32 blocks of 1024B, block
// index (nt*2+d)*4+s, content byte [lane*16+i] = digit d of
// W[hc*64 + nt*16 + (lane&15)][s*64 + (lane>>4)*16 + i].
__global__ __launch_bounds__(1024, 4) void snn_main(
    const uint32_t* __restrict__ Z, const float* __restrict__ Wh,
    const float* __restrict__ bh, const float* __restrict__ Wr,
    const float* __restrict__ br, float* __restrict__ out) {
  __shared__ __align__(16) char WS[131072];

  const int tid = threadIdx.x;
  const int b0  = blockIdx.x * 64;

  // ---- stage W -> LDS as i8 digit pair (a = rint(W*256), b = residual),
  //      written directly in MFMA-fragment order. 1024 thr: row r = tid&255,
  //      f-quarter w = tid>>8.
  {
    const int r = tid & 255;
    const int w = tid >> 8;
    const int hc2 = r >> 6, rr = r & 63;
    const int nt = rr >> 4, n = rr & 15;
    const float* wrow = Wh + (size_t)r * FF + w * 64;
    int4v* ws4 = (int4v*)(WS + hc2 * 32768);
#pragma unroll
    for (int q = 0; q < 4; ++q) {
      uint32_t pa[4], pb[4];
#pragma unroll
      for (int c4 = 0; c4 < 4; ++c4) {
        float4 w4 = *(const float4*)(wrow + q * 16 + c4 * 4);
        float wf[4] = {w4.x, w4.y, w4.z, w4.w};
        uint32_t ua = 0, ub = 0;
#pragma unroll
        for (int e = 0; e < 4; ++e) {
          float af = rintf(wf[e] * 256.0f);
          af = fminf(fmaxf(af, -127.0f), 127.0f);
          float bf = rintf(__builtin_fmaf(af, -64.0f, wf[e] * 16384.0f));
          bf = fminf(fmaxf(bf, -127.0f), 127.0f);
          int ai = (int)af, bi = (int)bf;
          ua |= ((uint32_t)ai & 255u) << (8 * e);
          ub |= ((uint32_t)bi & 255u) << (8 * e);
        }
        pa[c4] = ua; pb[c4] = ub;
      }
      ws4[((nt * 2 + 0) * 4 + w) * 64 + q * 16 + n] = *(int4v*)pa;
      ws4[((nt * 2 + 1) * 4 + w) * 64 + q * 16 + n] = *(int4v*)pb;
    }
  }
  __syncthreads();

  const int lane = tid & 63;
  const int wv   = tid >> 6;        // 0..15
  const int hc   = wv >> 2;         // h-chunk (0..3) -> 64 h-cols
  const int bsub = wv & 3;          // b-subtile (0..3) -> 16 b-rows
  const int h0   = hc * 64;
  const int col  = lane & 15;       // A: m-row / B: n-col / C: col
  const int quad = lane >> 4;
  const bool qhi = (quad & 2) != 0;       // which zb word pair
  const uint32_t shl16 = (quad & 1) * 16; // which halfword

  const int brow = b0 + bsub * 16 + col;  // A-operand b row for this lane

  const float K_VM = (float)(0.001 * 100.0);
  const float K_ID = (float)(1.0 - 0.001 * 200.0);

  float v2[4][4], ii[4][4];
  uint32_t sc[4][4];
#pragma unroll
  for (int nt = 0; nt < 4; ++nt)
#pragma unroll
    for (int r = 0; r < 4; ++r) { v2[nt][r] = 0.f; ii[nt][r] = 0.f; sc[nt][r] = 0u; }

  float bias[4];
#pragma unroll
  for (int nt = 0; nt < 4; ++nt) bias[nt] = bh[h0 + nt * 16 + col];

  // per-lane compacted spike halfwords: hwS<s>[j] = 16 bits this lane needs
  // at k-step s, t-plane j (bits [s*64 + quad*16 .. +15] of Z row brow)
  uint32_t hwS0[4], hwS1[4], hwS2[4], hwS3[4];
  const uint32_t* zrow = Z + (size_t)brow * 8;

  auto load_hw = [&](int tgi) {
#pragma unroll
    for (int j = 0; j < 4; ++j) {
      const uint32_t* p = zrow + ((size_t)tgi * 4 + j) * (size_t)(BB * 8);
      uint4 a = *(const uint4*)p;
      uint4 b4 = *(const uint4*)(p + 4);
      hwS0[j] = (qhi ? a.y : a.x) >> shl16;
      hwS1[j] = (qhi ? a.w : a.z) >> shl16;
      hwS2[j] = (qhi ? b4.y : b4.x) >> shl16;
      hwS3[j] = (qhi ? b4.w : b4.z) >> shl16;
    }
  };
  load_hw(0);

  // single runtime LDS base: this wave's hc slab + lane offset
  const char* wsl = WS + hc * 32768 + lane * 16;

#pragma unroll 1
  for (int tg = 0; tg < TT / 4; ++tg) {
    int4v acc[4][4];
#pragma unroll
    for (int j = 0; j < 4; ++j)
#pragma unroll
      for (int nt = 0; nt < 4; ++nt)
        acc[j][nt] = (int4v){0, 0, 0, 0};

    // ---- K loop: 4 steps of 64 f-columns, both digits fused ----
#pragma unroll 1
    for (int s = 0; s < 4; ++s) {
      const int4v* bp = (const int4v*)(wsl + s * 1024);
      int4v Ba[4], Bb[4];
#pragma unroll
      for (int nt = 0; nt < 4; ++nt) {
        Ba[nt] = bp[(nt * 2 + 0) * 256];  // imm offset (nt*2+0)*4096 B
        Bb[nt] = bp[(nt * 2 + 1) * 256];
      }
#pragma unroll
      for (int j = 0; j < 4; ++j) {
        uint32_t t0 = (s & 1) ? hwS1[j] : hwS0[j];
        uint32_t t1 = (s & 1) ? hwS3[j] : hwS2[j];
        uint32_t h16 = (s & 2) ? t1 : t0;
        int4v za, zb_;
#pragma unroll
        for (int p = 0; p < 4; ++p) {
          uint32_t nib = (h16 >> (4 * p)) & 15u;
          uint32_t zbyte = __umul24(nib, 0x204081u) & 0x01010101u;
          zb_[p] = (int)zbyte;
          za[p]  = (int)(zbyte << 6);  // 64*z, fits i8
        }
#pragma unroll
        for (int nt = 0; nt < 4; ++nt) {
          acc[j][nt] = __builtin_amdgcn_mfma_i32_16x16x64_i8(
              za, Ba[nt], acc[j][nt], 0, 0, 0);
          acc[j][nt] = __builtin_amdgcn_mfma_i32_16x16x64_i8(
              zb_, Bb[nt], acc[j][nt], 0, 0, 0);
        }
      }
    }

    // ---- prefetch next tg's spike bits (covered by LIF VALU) ----
    if (tg < TT / 4 - 1) load_hw(tg + 1);

    // ---- 4 sequential layer-2 LIF updates (numpy op order) ----
    // h = fl(acc*2^-14 + bias): cvt exact (|acc|<2^24), mul by 2^-14 exact.
#pragma unroll
    for (int j = 0; j < 4; ++j) {
#pragma unroll
      for (int nt = 0; nt < 4; ++nt) {
#pragma unroll
        for (int r = 0; r < 4; ++r) {
          float hq = __fmul_rn((float)acc[j][nt][r], 6.103515625e-05f);
          float h  = __fadd_rn(hq, bias[nt]);
          float vv = v2[nt][r], ci = ii[nt][r];
          float vd   = __fadd_rn(vv, __fmul_rn(K_VM, __fadd_rn(-vv, ci)));
          float idec = __fmul_rn(ci, K_ID);
          bool z = (vd > 1.0f);
          v2[nt][r] = z ? 0.0f : vd;
          ii[nt][r] = __fadd_rn(idec, h);
          sc[nt][r] += z ? 1u : 0u;
        }
      }
    }
  }

  // ---- epilogue: readout GEMM, fused ----
  // mean = (float)count / 100 : count exact in fp32, one div rounding (==np)
  float mean[4][4];
#pragma unroll
  for (int nt = 0; nt < 4; ++nt)
#pragma unroll
    for (int r = 0; r < 4; ++r) mean[nt][r] = __fdiv_rn((float)sc[nt][r], 100.0f);

#pragma unroll 1
  for (int c = 0; c < CC; ++c) {
    float wc[4];
#pragma unroll
    for (int nt = 0; nt < 4; ++nt) wc[nt] = Wr[c * HH + h0 + nt * 16 + col];
#pragma unroll
    for (int r = 0; r < 4; ++r) {
      float s = 0.f;
#pragma unroll
      for (int nt = 0; nt < 4; ++nt) s = fmaf(mean[nt][r], wc[nt], s);
      s += __shfl_xor(s, 1);
      s += __shfl_xor(s, 2);
      s += __shfl_xor(s, 4);
      s += __shfl_xor(s, 8);
      if (col == 0) {
        int b = b0 + bsub * 16 + quad * 4 + r;
        float add = s + ((hc == 0) ? br[c] : 0.0f);
        atomicAdd(&out[b * CC + c], add);
      }
    }
  }
}

extern "C" void kernel_launch(void* const* d_in, const int* in_sizes, int n_in,
                              void* d_out, int out_size, void* d_ws, size_t ws_size,
                              hipStream_t stream) {
  const float* x  = (const float*)d_in[0];
  const float* Wh = (const float*)d_in[1];
  const float* bh = (const float*)d_in[2];
  const float* Wr = (const float*)d_in[3];
  const float* br = (const float*)d_in[4];
  float* out = (float*)d_out;

  // workspace: spike bitmask, 100*16384*32B = 52.4 MB
  unsigned long long* Z = (unsigned long long*)d_ws;

  hipMemsetAsync(d_out, 0, (size_t)out_size * sizeof(float), stream);
  spike_gen<<<BB / 16, 256, 0, stream>>>(x, Z);
  snn_main<<<BB / 64, 1024, 0, stream>>>((const uint32_t*)Z, Wh, bh, Wr, br, out);
}

// Round 7
// 439.205 us; speedup vs baseline: 1.6268x; 1.6268x over previous
//
#include <hip/hip_runtime.h>
#include <hip/hip_fp16.h>
#include <stdint.h>

// SNNClassifier: B=16384, F=256, H=256, C=10, T=100
// Phase 1: layer-1 LIF spike bitmask into d_ws (100 x 16384 x 256 bits).
// Phase 2: persistent-state fused kernel, int8 fused-digit GEMM:
//   W*2^14 = a*64 + b (a,b int8 digits); h = (sum a*(64 z) + b*z)*2^-14
//   via mfma_i32_16x16x64_i8, single exact i32 accumulator.
//
// R7 (R6 post-mortem: forcing 16-wave blocks into 128 regs/wave spilled
// 1.5GB. R5's real binds: 164 regs/wave -> 3 waves/SIMD, and 1024 jobs on
// 768 slots -> ceil(4/3)=2 rounds/CU = 50% tail waste):
//  1. Wave tile 16b x 32h (nt=2): acc 32 AGPR, live set ~110 unified ->
//     4 waves/SIMD genuinely fits the 128-reg budget (unlike R6).
//     Grid = 256 bc x 8 hc = 2048 blocks = 8/CU over 4 resident = 2 exact
//     rounds, ZERO tail. Cost: unpack VALU 2x (A-frag feeds 4 MFMAs not 8)
//     -- chip VALU ~150us, still far below R5's tail-driven 306.
//  2. spike_gen: wave-per-b (4 states/thread), ballot fused into the z
//     compare (v_cmp writes the sgpr mask directly), tiny reg footprint ->
//     8 waves/SIMD latency hiding.
// Integer accumulation is order-free -> absmax must stay bit-identical
// (0.003417969). Any change = mapping bug.

#define BB 16384
#define FF 256
#define HH 256
#define CC 10
#define TT 100

typedef __attribute__((ext_vector_type(4))) int int4v;

// ---------------- kernel 1: layer-1 spike bitmask ----------------
// Wave owns ONE b: thread state seg 0..3 (f = seg*64 + lane). Ballot per
// seg; lanes 0..3 hold the 4 u64 masks, one 32B store per t.
__global__ __launch_bounds__(256) void spike_gen(
    const float* __restrict__ x, unsigned long long* __restrict__ Z) {
  const int lane = threadIdx.x & 63;
  const int wv   = threadIdx.x >> 6;
  const int b    = blockIdx.x * 4 + wv;
  const float K_VM = (float)(0.001 * 100.0);        // 0.1f, numpy-exact
  const float K_ID = (float)(1.0 - 0.001 * 200.0);  // 0.8f, numpy-exact

  float v[4], cur[4], xv[4];
#pragma unroll
  for (int s = 0; s < 4; ++s) {
    xv[s] = x[(size_t)b * FF + s * 64 + lane];
    v[s] = 0.0f; cur[s] = 0.0f;
  }

  unsigned long long* zp = Z + (size_t)b * 4;  // u64 units; +lane for seg

  for (int t = 0; t < TT; ++t) {
    unsigned long long bal[4];
#pragma unroll
    for (int s = 0; s < 4; ++s) {
      float vd   = __fadd_rn(v[s], __fmul_rn(K_VM, __fadd_rn(-v[s], cur[s])));
      float idec = __fmul_rn(cur[s], K_ID);
      bool z = (vd > 1.0f);
      bal[s] = __ballot(z);          // v_cmp result IS the mask
      v[s]   = z ? 0.0f : vd;
      cur[s] = __fadd_rn(idec, xv[s]);
    }
    unsigned long long m = (lane & 2) ? ((lane & 1) ? bal[3] : bal[2])
                                      : ((lane & 1) ? bal[1] : bal[0]);
    if (lane < 4) zp[(size_t)t * (BB * 4) + lane] = m;
  }
}

// ---------------- kernel 2: fused temporal loop (i8) ----------------
// grid: 2048 blocks = 256 bc x 8 hc (bc = bx>>3, hc = bx&7 -> hc-adjacent
// blocks share Z rows in L2). block = 256 thr = 4 waves = 4 b-subtiles of
// 16 rows; all waves share one 32-h chunk.
// LDS slab 16KB: 16 blocks of 1024B, index (nt*2+d)*4+s (nt<2, d<2, s<4),
// content byte [lane*16+i] = digit d of
//   W[h0 + nt*16 + (lane&15)][s*64 + (lane>>4)*16 + i].
__global__ __launch_bounds__(256, 4) void snn_main(
    const uint32_t* __restrict__ Z, const float* __restrict__ Wh,
    const float* __restrict__ bh, const float* __restrict__ Wr,
    const float* __restrict__ br, float* __restrict__ out) {
  __shared__ __align__(16) char WS[16384];

  const int tid = threadIdx.x;
  const int bx  = blockIdx.x;
  const int hc  = bx & 7;
  const int bc  = bx >> 3;
  const int h0  = hc * 32;
  const int b0  = bc * 64;

  // ---- stage W -> LDS as i8 digit pair, MFMA-fragment order ----
  // 512 units: u = rr*16 + s*4 + kq; unit writes 16B per digit.
  {
    int4v* ws4 = (int4v*)WS;
#pragma unroll
    for (int half = 0; half < 2; ++half) {
      const int u  = tid + half * 256;
      const int rr = u >> 4;            // 0..31 h-row
      const int q  = u & 15;
      const int s  = q >> 2, kq = q & 3;
      const int nt = rr >> 4, n = rr & 15;
      const float* wp = Wh + (size_t)(h0 + rr) * FF + s * 64 + kq * 16;
      uint32_t pa[4], pb[4];
#pragma unroll
      for (int c4 = 0; c4 < 4; ++c4) {
        float4 w4 = *(const float4*)(wp + c4 * 4);
        float wf[4] = {w4.x, w4.y, w4.z, w4.w};
        uint32_t ua = 0, ub = 0;
#pragma unroll
        for (int e = 0; e < 4; ++e) {
          float af = rintf(wf[e] * 256.0f);
          af = fminf(fmaxf(af, -127.0f), 127.0f);
          float bf = rintf(__builtin_fmaf(af, -64.0f, wf[e] * 16384.0f));
          bf = fminf(fmaxf(bf, -127.0f), 127.0f);
          ua |= ((uint32_t)((int)af) & 255u) << (8 * e);
          ub |= ((uint32_t)((int)bf) & 255u) << (8 * e);
        }
        pa[c4] = ua; pb[c4] = ub;
      }
      // fragment slot: block (nt*2+d)*4+s, byte offset (n + 16*kq)*16
      ws4[((nt * 2 + 0) * 4 + s) * 64 + kq * 16 + n] = *(int4v*)pa;
      ws4[((nt * 2 + 1) * 4 + s) * 64 + kq * 16 + n] = *(int4v*)pb;
    }
  }
  __syncthreads();

  const int lane = tid & 63;
  const int bsub = tid >> 6;        // wave -> b-subtile
  const int col  = lane & 15;       // A: m-row / B: n-col / C: col
  const int quad = lane >> 4;
  const bool qhi = (quad & 2) != 0;       // which zb word pair
  const uint32_t shl16 = (quad & 1) * 16; // which halfword

  const int brow = b0 + bsub * 16 + col;  // A-operand b row for this lane

  const float K_VM = (float)(0.001 * 100.0);
  const float K_ID = (float)(1.0 - 0.001 * 200.0);

  float v2[2][4], ii[2][4];
  uint32_t sc[2][4];
#pragma unroll
  for (int nt = 0; nt < 2; ++nt)
#pragma unroll
    for (int r = 0; r < 4; ++r) { v2[nt][r] = 0.f; ii[nt][r] = 0.f; sc[nt][r] = 0u; }

  float bias[2];
#pragma unroll
  for (int nt = 0; nt < 2; ++nt) bias[nt] = bh[h0 + nt * 16 + col];

  // per-lane compacted spike halfwords: hwS<s>[j] = 16 bits this lane needs
  // at k-step s, t-plane j (bits [s*64 + quad*16 .. +15] of Z row brow)
  uint32_t hwS0[4], hwS1[4], hwS2[4], hwS3[4];
  const uint32_t* zrow = Z + (size_t)brow * 8;

  auto load_hw = [&](int tgi) {
#pragma unroll
    for (int j = 0; j < 4; ++j) {
      const uint32_t* p = zrow + ((size_t)tgi * 4 + j) * (size_t)(BB * 8);
      uint4 a = *(const uint4*)p;
      uint4 b4 = *(const uint4*)(p + 4);
      hwS0[j] = (qhi ? a.y : a.x) >> shl16;
      hwS1[j] = (qhi ? a.w : a.z) >> shl16;
      hwS2[j] = (qhi ? b4.y : b4.x) >> shl16;
      hwS3[j] = (qhi ? b4.w : b4.z) >> shl16;
    }
  };
  load_hw(0);

  const char* wsl = WS + lane * 16;  // single runtime LDS base

#pragma unroll 1
  for (int tg = 0; tg < TT / 4; ++tg) {
    int4v acc[4][2];
#pragma unroll
    for (int j = 0; j < 4; ++j)
#pragma unroll
      for (int nt = 0; nt < 2; ++nt)
        acc[j][nt] = (int4v){0, 0, 0, 0};

    // ---- K loop: 4 steps of 64 f-columns, both digits fused ----
#pragma unroll 1
    for (int s = 0; s < 4; ++s) {
      const int4v* bp = (const int4v*)(wsl + s * 1024);
      int4v Ba[2], Bb[2];
#pragma unroll
      for (int nt = 0; nt < 2; ++nt) {
        Ba[nt] = bp[(nt * 2 + 0) * 256];  // imm offset (nt*2+d)*4096 B
        Bb[nt] = bp[(nt * 2 + 1) * 256];
      }
#pragma unroll
      for (int j = 0; j < 4; ++j) {
        uint32_t t0 = (s & 1) ? hwS1[j] : hwS0[j];
        uint32_t t1 = (s & 1) ? hwS3[j] : hwS2[j];
        uint32_t h16 = (s & 2) ? t1 : t0;
        int4v za, zb_;
#pragma unroll
        for (int p = 0; p < 4; ++p) {
          uint32_t nib = (h16 >> (4 * p)) & 15u;
          uint32_t zbyte = __umul24(nib, 0x204081u) & 0x01010101u;
          zb_[p] = (int)zbyte;
          za[p]  = (int)(zbyte << 6);  // 64*z, fits i8
        }
#pragma unroll
        for (int nt = 0; nt < 2; ++nt) {
          acc[j][nt] = __builtin_amdgcn_mfma_i32_16x16x64_i8(
              za, Ba[nt], acc[j][nt], 0, 0, 0);
          acc[j][nt] = __builtin_amdgcn_mfma_i32_16x16x64_i8(
              zb_, Bb[nt], acc[j][nt], 0, 0, 0);
        }
      }
    }

    // ---- prefetch next tg's spike bits (covered by LIF VALU) ----
    if (tg < TT / 4 - 1) load_hw(tg + 1);

    // ---- 4 sequential layer-2 LIF updates (numpy op order) ----
    // h = fl(acc*2^-14 + bias): cvt exact (|acc|<2^24), mul by 2^-14 exact.
#pragma unroll
    for (int j = 0; j < 4; ++j) {
#pragma unroll
      for (int nt = 0; nt < 2; ++nt) {
#pragma unroll
        for (int r = 0; r < 4; ++r) {
          float hq = __fmul_rn((float)acc[j][nt][r], 6.103515625e-05f);
          float h  = __fadd_rn(hq, bias[nt]);
          float vv = v2[nt][r], ci = ii[nt][r];
          float vd   = __fadd_rn(vv, __fmul_rn(K_VM, __fadd_rn(-vv, ci)));
          float idec = __fmul_rn(ci, K_ID);
          bool z = (vd > 1.0f);
          v2[nt][r] = z ? 0.0f : vd;
          ii[nt][r] = __fadd_rn(idec, h);
          sc[nt][r] += z ? 1u : 0u;
        }
      }
    }
  }

  // ---- epilogue: readout GEMM, fused ----
  float mean[2][4];
#pragma unroll
  for (int nt = 0; nt < 2; ++nt)
#pragma unroll
    for (int r = 0; r < 4; ++r) mean[nt][r] = __fdiv_rn((float)sc[nt][r], 100.0f);

#pragma unroll 1
  for (int c = 0; c < CC; ++c) {
    float wc[2];
#pragma unroll
    for (int nt = 0; nt < 2; ++nt) wc[nt] = Wr[c * HH + h0 + nt * 16 + col];
#pragma unroll
    for (int r = 0; r < 4; ++r) {
      float s = fmaf(mean[0][r], wc[0], 0.f);
      s = fmaf(mean[1][r], wc[1], s);
      s += __shfl_xor(s, 1);
      s += __shfl_xor(s, 2);
      s += __shfl_xor(s, 4);
      s += __shfl_xor(s, 8);
      if (col == 0) {
        int b = b0 + bsub * 16 + quad * 4 + r;
        float add = s + ((hc == 0) ? br[c] : 0.0f);
        atomicAdd(&out[b * CC + c], add);
      }
    }
  }
}

extern "C" void kernel_launch(void* const* d_in, const int* in_sizes, int n_in,
                              void* d_out, int out_size, void* d_ws, size_t ws_size,
                              hipStream_t stream) {
  const float* x  = (const float*)d_in[0];
  const float* Wh = (const float*)d_in[1];
  const float* bh = (const float*)d_in[2];
  const float* Wr = (const float*)d_in[3];
  const float* br = (const float*)d_in[4];
  float* out = (float*)d_out;

  // workspace: spike bitmask, 100*16384*32B = 52.4 MB
  unsigned long long* Z = (unsigned long long*)d_ws;

  hipMemsetAsync(d_out, 0, (size_t)out_size * sizeof(float), stream);
  spike_gen<<<BB / 4, 256, 0, stream>>>(x, Z);
  snn_main<<<2048, 256, 0, stream>>>((const uint32_t*)Z, Wh, bh, Wr, br, out);
}

// Round 8
// 389.783 us; speedup vs baseline: 1.8331x; 1.1268x over previous
//
#include <hip/hip_runtime.h>
#include <hip/hip_fp16.h>
#include <stdint.h>

// SNNClassifier: B=16384, F=256, H=256, C=10, T=100
// Phase 1: layer-1 LIF spike bitmask into d_ws (100 x 16384 x 256 bits).
// Phase 2: persistent-state fused kernel, int8 fused-digit GEMM:
//   W*2^14 = a*64 + b (i8 digits); h = (sum a*(64z) + b*z)*2^-14 via
//   mfma_i32_16x16x64_i8, single exact i32 accumulator.
//
// R8 (calibrated counters: MfmaUtil/VALUBusy are per-SIMD; one i8 MFMA is
// ~20 SIMD-cyc. R7: MFMA pipe at 87% of its floor, VALU = 3x MFMA cycles
// -> purely VALU-issue-bound; unpack work duplicated D=H/H_wave times):
//  1. nt=4, j=2 (tg=2): H_wave 64 -> unpack duplication D 8->4, Z fetch
//     halves. Acc halves to 32 AGPR so the wave fits 128 unified regs
//     (R5-measured 164 - 32 acc - 8 hw - 12 sc = 112): true 4 waves/SIMD.
//     Grid = 256bc x 4hc = 1024 blocks = EXACTLY 4/CU, one round, no tail.
//     LDS 4 x 32KB = 128 <= 160KB.
//  2. h = fma(cvt(acc), 2^-14, bias): product is exact (pow2 scale of int
//     < 2^22), so single-rounding fma is bit-identical to mul+add. -1 op/el.
//  3. sc packed 4 counters/reg (max 100 < 255): -12 regs.
//  4. spike_gen: 8 LIF states/thread (wave per 2 b) for 8-way ILP on the
//     serial v-chain + 3-level select tree instead of 8 lane-compares.
// Integer acc + identical FP order => absmax must stay EXACTLY 0.003417969.

#define BB 16384
#define FF 256
#define HH 256
#define CC 10
#define TT 100

typedef __attribute__((ext_vector_type(4))) int int4v;

// ---------------- kernel 1: layer-1 spike bitmask ----------------
// Wave owns TWO b: 8 states/thread (jb<2 x js<4). Lanes 0..7 store 8 u64
// = 64B contiguous per t.
__global__ __launch_bounds__(256) void spike_gen(
    const float* __restrict__ x, unsigned long long* __restrict__ Z) {
  const int lane = threadIdx.x & 63;
  const int wv   = threadIdx.x >> 6;
  const int b0   = blockIdx.x * 8 + wv * 2;
  const float K_VM = (float)(0.001 * 100.0);        // 0.1f, numpy-exact
  const float K_ID = (float)(1.0 - 0.001 * 200.0);  // 0.8f, numpy-exact

  float v[8], cur[8], xv[8];
#pragma unroll
  for (int jb = 0; jb < 2; ++jb)
#pragma unroll
    for (int js = 0; js < 4; ++js) {
      const int idx = jb * 4 + js;
      xv[idx] = x[(size_t)(b0 + jb) * FF + js * 64 + lane];
      v[idx] = 0.0f; cur[idx] = 0.0f;
    }

  const bool s0 = (lane & 1) != 0, s1 = (lane & 2) != 0, s2 = (lane & 4) != 0;
  unsigned long long* zp = Z + (size_t)b0 * 4;

  for (int t = 0; t < TT; ++t) {
    unsigned long long bal[8];
#pragma unroll
    for (int idx = 0; idx < 8; ++idx) {
      float vd   = __fadd_rn(v[idx], __fmul_rn(K_VM, __fadd_rn(-v[idx], cur[idx])));
      float idec = __fmul_rn(cur[idx], K_ID);
      bool z = (vd > 1.0f);
      bal[idx] = __ballot(z);
      v[idx]   = z ? 0.0f : vd;
      cur[idx] = __fadd_rn(idec, xv[idx]);
    }
    // 3-level select tree: lane idx (0..7) picks bal[idx]
    unsigned long long m0 = s0 ? bal[1] : bal[0];
    unsigned long long m1 = s0 ? bal[3] : bal[2];
    unsigned long long m2 = s0 ? bal[5] : bal[4];
    unsigned long long m3 = s0 ? bal[7] : bal[6];
    unsigned long long n0 = s1 ? m1 : m0;
    unsigned long long n1 = s1 ? m3 : m2;
    unsigned long long m  = s2 ? n1 : n0;
    if (lane < 8) zp[(size_t)t * (BB * 4) + lane] = m;
  }
}

// ---------------- kernel 2: fused temporal loop (i8) ----------------
// grid: 1024 blocks = 256 bc x 4 hc (hc = bx&3 -> hc-adjacent blocks share
// Z rows in L2). block = 256 thr = 4 waves = 4 b-subtiles of 16 rows; all
// waves share one 64-h chunk (nt=4). 2 t-planes per group (j=2).
// LDS slab 32KB: 32 blocks of 1024B, index (nt*2+d)*4+s, content byte
// [lane*16+i] = digit d of W[h0+nt*16+(lane&15)][s*64+(lane>>4)*16+i].
__global__ __launch_bounds__(256, 4) void snn_main(
    const uint32_t* __restrict__ Z, const float* __restrict__ Wh,
    const float* __restrict__ bh, const float* __restrict__ Wr,
    const float* __restrict__ br, float* __restrict__ out) {
  __shared__ __align__(16) char WS[32768];

  const int tid = threadIdx.x;
  const int bx  = blockIdx.x;
  const int hc  = bx & 3;
  const int bc  = bx >> 2;
  const int h0  = hc * 64;
  const int b0  = bc * 64;

  // ---- stage W -> LDS as i8 digit pair, MFMA-fragment order ----
  // 1024 units: u = rr*16 + s*4 + kq (rr<64); each writes 16B per digit.
  {
    int4v* ws4 = (int4v*)WS;
#pragma unroll
    for (int half = 0; half < 4; ++half) {
      const int u  = tid + half * 256;
      const int rr = u >> 4;
      const int q  = u & 15;
      const int s  = q >> 2, kq = q & 3;
      const int nt = rr >> 4, n = rr & 15;
      const float* wp = Wh + (size_t)(h0 + rr) * FF + s * 64 + kq * 16;
      uint32_t pa[4], pb[4];
#pragma unroll
      for (int c4 = 0; c4 < 4; ++c4) {
        float4 w4 = *(const float4*)(wp + c4 * 4);
        float wf[4] = {w4.x, w4.y, w4.z, w4.w};
        uint32_t ua = 0, ub = 0;
#pragma unroll
        for (int e = 0; e < 4; ++e) {
          float af = rintf(wf[e] * 256.0f);
          af = fminf(fmaxf(af, -127.0f), 127.0f);
          float bf = rintf(__builtin_fmaf(af, -64.0f, wf[e] * 16384.0f));
          bf = fminf(fmaxf(bf, -127.0f), 127.0f);
          ua |= ((uint32_t)((int)af) & 255u) << (8 * e);
          ub |= ((uint32_t)((int)bf) & 255u) << (8 * e);
        }
        pa[c4] = ua; pb[c4] = ub;
      }
      ws4[((nt * 2 + 0) * 4 + s) * 64 + kq * 16 + n] = *(int4v*)pa;
      ws4[((nt * 2 + 1) * 4 + s) * 64 + kq * 16 + n] = *(int4v*)pb;
    }
  }
  __syncthreads();

  const int lane = tid & 63;
  const int bsub = tid >> 6;
  const int col  = lane & 15;
  const int quad = lane >> 4;
  const bool qhi = (quad & 2) != 0;
  const uint32_t shl16 = (quad & 1) * 16;

  const int brow = b0 + bsub * 16 + col;

  const float K_VM = (float)(0.001 * 100.0);
  const float K_ID = (float)(1.0 - 0.001 * 200.0);

  float v2[4][4], ii[4][4];
  uint32_t sc[4];  // packed: byte r of sc[nt] = spike count (<=100)
#pragma unroll
  for (int nt = 0; nt < 4; ++nt) {
    sc[nt] = 0u;
#pragma unroll
    for (int r = 0; r < 4; ++r) { v2[nt][r] = 0.f; ii[nt][r] = 0.f; }
  }

  float bias[4];
#pragma unroll
  for (int nt = 0; nt < 4; ++nt) bias[nt] = bh[h0 + nt * 16 + col];

  // per-lane compacted spike halfwords for 2 t-planes
  uint32_t hwS0[2], hwS1[2], hwS2[2], hwS3[2];
  const uint32_t* zrow = Z + (size_t)brow * 8;

  auto load_hw = [&](int tgi) {
#pragma unroll
    for (int j = 0; j < 2; ++j) {
      const uint32_t* p = zrow + ((size_t)tgi * 2 + j) * (size_t)(BB * 8);
      uint4 a = *(const uint4*)p;
      uint4 b4 = *(const uint4*)(p + 4);
      hwS0[j] = (qhi ? a.y : a.x) >> shl16;
      hwS1[j] = (qhi ? a.w : a.z) >> shl16;
      hwS2[j] = (qhi ? b4.y : b4.x) >> shl16;
      hwS3[j] = (qhi ? b4.w : b4.z) >> shl16;
    }
  };
  load_hw(0);

  const char* wsl = WS + lane * 16;

#pragma unroll 1
  for (int tg = 0; tg < TT / 2; ++tg) {
    int4v acc[2][4];
#pragma unroll
    for (int j = 0; j < 2; ++j)
#pragma unroll
      for (int nt = 0; nt < 4; ++nt)
        acc[j][nt] = (int4v){0, 0, 0, 0};

    // ---- K loop: 4 steps of 64 f-columns, both digits fused ----
#pragma unroll 1
    for (int s = 0; s < 4; ++s) {
      const int4v* bp = (const int4v*)(wsl + s * 1024);
      int4v Ba[4], Bb[4];
#pragma unroll
      for (int nt = 0; nt < 4; ++nt) {
        Ba[nt] = bp[(nt * 2 + 0) * 256];  // imm offset (nt*2+d)*4096 B
        Bb[nt] = bp[(nt * 2 + 1) * 256];
      }
#pragma unroll
      for (int j = 0; j < 2; ++j) {
        uint32_t t0 = (s & 1) ? hwS1[j] : hwS0[j];
        uint32_t t1 = (s & 1) ? hwS3[j] : hwS2[j];
        uint32_t h16 = (s & 2) ? t1 : t0;
        int4v za, zb_;
#pragma unroll
        for (int p = 0; p < 4; ++p) {
          uint32_t nib = (h16 >> (4 * p)) & 15u;
          uint32_t zbyte = __umul24(nib, 0x204081u) & 0x01010101u;
          zb_[p] = (int)zbyte;
          za[p]  = (int)(zbyte << 6);  // 64*z, fits i8
        }
#pragma unroll
        for (int nt = 0; nt < 4; ++nt) {
          acc[j][nt] = __builtin_amdgcn_mfma_i32_16x16x64_i8(
              za, Ba[nt], acc[j][nt], 0, 0, 0);
          acc[j][nt] = __builtin_amdgcn_mfma_i32_16x16x64_i8(
              zb_, Bb[nt], acc[j][nt], 0, 0, 0);
        }
      }
    }

    // ---- prefetch next tg's spike bits (covered by LIF VALU) ----
    if (tg < TT / 2 - 1) load_hw(tg + 1);

    // ---- 2 sequential layer-2 LIF updates (numpy op order) ----
    // h = fma(cvt(acc), 2^-14, bias): product exact -> bit-identical to
    // the two-rounding form.
#pragma unroll
    for (int j = 0; j < 2; ++j) {
#pragma unroll
      for (int nt = 0; nt < 4; ++nt) {
#pragma unroll
        for (int r = 0; r < 4; ++r) {
          float h  = __builtin_fmaf((float)acc[j][nt][r], 6.103515625e-05f,
                                    bias[nt]);
          float vv = v2[nt][r], ci = ii[nt][r];
          float vd   = __fadd_rn(vv, __fmul_rn(K_VM, __fadd_rn(-vv, ci)));
          float idec = __fmul_rn(ci, K_ID);
          bool z = (vd > 1.0f);
          v2[nt][r] = z ? 0.0f : vd;
          ii[nt][r] = __fadd_rn(idec, h);
          sc[nt] += (z ? 1u : 0u) << (8 * r);
        }
      }
    }
  }

  // ---- epilogue: readout GEMM, fused ----
  float mean[4][4];
#pragma unroll
  for (int nt = 0; nt < 4; ++nt)
#pragma unroll
    for (int r = 0; r < 4; ++r)
      mean[nt][r] = __fdiv_rn((float)((sc[nt] >> (8 * r)) & 255u), 100.0f);

#pragma unroll 1
  for (int c = 0; c < CC; ++c) {
    float wc[4];
#pragma unroll
    for (int nt = 0; nt < 4; ++nt) wc[nt] = Wr[c * HH + h0 + nt * 16 + col];
#pragma unroll
    for (int r = 0; r < 4; ++r) {
      float s = 0.f;
#pragma unroll
      for (int nt = 0; nt < 4; ++nt) s = fmaf(mean[nt][r], wc[nt], s);
      s += __shfl_xor(s, 1);
      s += __shfl_xor(s, 2);
      s += __shfl_xor(s, 4);
      s += __shfl_xor(s, 8);
      if (col == 0) {
        int b = b0 + bsub * 16 + quad * 4 + r;
        float add = s + ((hc == 0) ? br[c] : 0.0f);
        atomicAdd(&out[b * CC + c], add);
      }
    }
  }
}

extern "C" void kernel_launch(void* const* d_in, const int* in_sizes, int n_in,
                              void* d_out, int out_size, void* d_ws, size_t ws_size,
                              hipStream_t stream) {
  const float* x  = (const float*)d_in[0];
  const float* Wh = (const float*)d_in[1];
  const float* bh = (const float*)d_in[2];
  const float* Wr = (const float*)d_in[3];
  const float* br = (const float*)d_in[4];
  float* out = (float*)d_out;

  // workspace: spike bitmask, 100*16384*32B = 52.4 MB
  unsigned long long* Z = (unsigned long long*)d_ws;

  hipMemsetAsync(d_out, 0, (size_t)out_size * sizeof(float), stream);
  spike_gen<<<BB / 8, 256, 0, stream>>>(x, Z);
  snn_main<<<1024, 256, 0, stream>>>((const uint32_t*)Z, Wh, bh, Wr, br, out);
}